// Round 1
// baseline (1564.381 us; speedup 1.0000x reference)
//
#include <hip/hip_runtime.h>
#include <math.h>

typedef __bf16 bf16x8 __attribute__((ext_vector_type(8)));
typedef __bf16 bf16x4 __attribute__((ext_vector_type(4)));
typedef float f32x4 __attribute__((ext_vector_type(4)));

#define NEG_HUGE -3.402823466e38f

__device__ __forceinline__ float wave_reduce_sum(float v) {
#pragma unroll
  for (int off = 32; off; off >>= 1) v += __shfl_xor(v, off);
  return v;
}
__device__ __forceinline__ float wave_reduce_max(float v) {
#pragma unroll
  for (int off = 32; off; off >>= 1) v = fmaxf(v, __shfl_xor(v, off));
  return v;
}

__device__ __forceinline__ void gload_lds16(const void* g, void* l) {
  __builtin_amdgcn_global_load_lds(
      (const __attribute__((address_space(1))) unsigned int*)g,
      (__attribute__((address_space(3))) unsigned int*)l, 16, 0, 0);
}

// ---------------- f32 -> bf16 conversion (weights) ----------------
__global__ void convert_bf16_kernel(const float* __restrict__ in,
                                    __bf16* __restrict__ out, long n4) {
  long i = (long)blockIdx.x * blockDim.x + threadIdx.x;
  if (i >= n4) return;
  long b = i * 4;
  float4 v = *(const float4*)(in + b);
  bf16x4 o;
  o.x = (__bf16)v.x; o.y = (__bf16)v.y; o.z = (__bf16)v.z; o.w = (__bf16)v.w;
  *(bf16x4*)(out + b) = o;
}

// ---------------- precompute sp[P], sc[C] ----------------
__global__ void pc_kernel(const float* __restrict__ prompt_embs,
                          const float* __restrict__ count_table,
                          const float* __restrict__ scorer_W,
                          float* __restrict__ sp, float* __restrict__ sc,
                          int P, int C, int D) {
  int gt = blockIdx.x * blockDim.x + threadIdx.x;
  int wid = gt >> 6;
  int lane = gt & 63;
  if (wid >= P + C) return;
  const float* row;
  const float* w;
  if (wid < P) { row = prompt_embs + (long)wid * D; w = scorer_W; }
  else         { row = count_table + (long)(wid - P) * D; w = scorer_W + 4 * D; }
  float acc = 0.f;
  for (int j = lane * 4; j < D; j += 256) {
    float4 a = *(const float4*)(row + j);
    float4 b = *(const float4*)(w + j);
    acc += a.x * b.x + a.y * b.y + a.z * b.z + a.w * b.w;
  }
  acc = wave_reduce_sum(acc);
  if (lane == 0) {
    if (wid < P) sp[wid] = acc; else sc[wid - P] = acc;
  }
}

// ---------------- per-edge score ----------------
__global__ __launch_bounds__(256)
void score_kernel(const float* __restrict__ ent, const float* __restrict__ nbr,
                  const float* __restrict__ rel,
                  const float* __restrict__ scorer_W,
                  const float* __restrict__ scorer_b,
                  const float* __restrict__ sp, const float* __restrict__ sc,
                  const int* __restrict__ counts, const int* __restrict__ pidx,
                  float* __restrict__ score, int N, int D) {
  int w = (blockIdx.x * 256 + threadIdx.x) >> 6;
  int lane = threadIdx.x & 63;
  if (w >= N) return;
  const long base = (long)w * D;
  const float* we = scorer_W + D;
  const float* wn = scorer_W + 2 * D;
  const float* wr = scorer_W + 3 * D;
  float acc = 0.f;
  for (int col = lane * 4; col < D; col += 256) {
    float4 a, b;
    a = *(const float4*)(ent + base + col);
    b = *(const float4*)(we + col);
    acc += a.x * b.x + a.y * b.y + a.z * b.z + a.w * b.w;
    a = *(const float4*)(nbr + base + col);
    b = *(const float4*)(wn + col);
    acc += a.x * b.x + a.y * b.y + a.z * b.z + a.w * b.w;
    a = *(const float4*)(rel + base + col);
    b = *(const float4*)(wr + col);
    acc += a.x * b.x + a.y * b.y + a.z * b.z + a.w * b.w;
  }
  acc = wave_reduce_sum(acc);
  if (lane == 0) {
    score[w] = acc + sp[pidx[w]] + sc[counts[w]] + scorer_b[0];
  }
}

// ---------------- segment starts (entity_indices sorted) ----------------
__global__ void segstart_kernel(const int* __restrict__ eidx,
                                int* __restrict__ segstart, int N, int E) {
  int n = blockIdx.x * blockDim.x + threadIdx.x;
  if (n > N) return;
  if (n == 0) {
    int cur = eidx[0];
    for (int e = 0; e <= cur; ++e) segstart[e] = 0;
  } else if (n == N) {
    int last = eidx[N - 1];
    for (int e = last + 1; e <= E; ++e) segstart[e] = N;
  } else {
    int prev = eidx[n - 1], cur = eidx[n];
    for (int e = prev + 1; e <= cur; ++e) segstart[e] = n;
  }
}

// ---------------- per-segment softmax + aggregation (block = 192 = D/4) ----
__global__ __launch_bounds__(192)
void agg_kernel(const float* __restrict__ ent, const float* __restrict__ rel,
                const float* __restrict__ count_table,
                const int* __restrict__ counts,
                const float* __restrict__ score,
                const int* __restrict__ segstart,
                __bf16* __restrict__ ent_agg, __bf16* __restrict__ rel_agg,
                int E, int D) {
  const int e = blockIdx.x;
  const int tid = threadIdx.x;
  int s = 0, t = 0;
  if (e < E) { s = segstart[e]; t = segstart[e + 1]; }
  const int cnt = t - s;
  __shared__ float sh[2];
  if (cnt > 0 && tid < 64) {
    float mx = NEG_HUGE;
    for (int n = s + tid; n < t; n += 64) mx = fmaxf(mx, score[n]);
    mx = wave_reduce_max(mx);
    float sum = 0.f;
    for (int n = s + tid; n < t; n += 64) sum += __expf(score[n] - mx);
    sum = wave_reduce_sum(sum);
    if (tid == 0) { sh[0] = mx; sh[1] = 1.f / sum; }
  }
  __syncthreads();
  float4 ae = {0.f, 0.f, 0.f, 0.f};
  float4 ar = {0.f, 0.f, 0.f, 0.f};
  float4 ac = {0.f, 0.f, 0.f, 0.f};
  const int col = tid * 4;
  if (cnt > 0) {
    const float mx = sh[0], inv = sh[1];
    for (int n = s; n < t; ++n) {
      const float w = __expf(score[n] - mx) * inv;
      const float4 ev = *(const float4*)(ent + (long)n * D + col);
      const float4 rv = *(const float4*)(rel + (long)n * D + col);
      const float4 cv = *(const float4*)(count_table + (long)counts[n] * D + col);
      ae.x += ev.x; ae.y += ev.y; ae.z += ev.z; ae.w += ev.w;
      ar.x += w * rv.x; ar.y += w * rv.y; ar.z += w * rv.z; ar.w += w * rv.w;
      ac.x += w * cv.x; ac.y += w * cv.y; ac.z += w * cv.z; ac.w += w * cv.w;
    }
    const float ic = 1.f / (float)cnt;
    ae.x *= ic; ae.y *= ic; ae.z *= ic; ae.w *= ic;
  }
  bf16x4 o;
  o.x = (__bf16)ae.x; o.y = (__bf16)ae.y; o.z = (__bf16)ae.z; o.w = (__bf16)ae.w;
  *(bf16x4*)(ent_agg + (long)e * D + col) = o;
  o.x = (__bf16)ar.x; o.y = (__bf16)ar.y; o.z = (__bf16)ar.z; o.w = (__bf16)ar.w;
  *(bf16x4*)(rel_agg + (long)e * 2 * D + col) = o;
  o.x = (__bf16)ac.x; o.y = (__bf16)ac.y; o.z = (__bf16)ac.z; o.w = (__bf16)ac.w;
  *(bf16x4*)(rel_agg + (long)e * 2 * D + D + col) = o;
}

// ---------------- bf16 NT GEMM: C[M,Nout] = A[M,K] * B[Nout,K]^T + bias ----
// 128x128 block, BK=32, 4 waves in 2x2, each wave 64x64 via 4x4 MFMA 16x16x32.
__global__ __launch_bounds__(256)
void gemm_bt_bias(const __bf16* __restrict__ A, const __bf16* __restrict__ B,
                  const float* __restrict__ bias, float* __restrict__ Cout,
                  int K, int Nout, int Mstore) {
  __shared__ __bf16 sA[128 * 32];
  __shared__ __bf16 sB[128 * 32];
  const int tid = threadIdx.x;
  const int wave = tid >> 6, lane = tid & 63;
  const int bm = blockIdx.x, bn = blockIdx.y;
  const int wm = wave >> 1, wn = wave & 1;

  // staging: thread t loads 16B: row = t>>2 (+64/issue), col elem = (t&3)*8
  const int ldrow = tid >> 2;
  const int ldcol = (tid & 3) * 8;
  const __bf16* Ap = A + (long)(bm * 128 + ldrow) * K + ldcol;
  const __bf16* Bp = B + (long)(bn * 128 + ldrow) * K + ldcol;
  char* sAb = (char*)sA + (size_t)wave * 1024;  // lane i -> +i*16
  char* sBb = (char*)sB + (size_t)wave * 1024;

  f32x4 acc[4][4] = {};

  const int fr = lane & 15;
  const int kk = (lane >> 4) * 8;

  for (int k0 = 0; k0 < K; k0 += 32) {
    __syncthreads();  // previous compute done before overwrite
    gload_lds16(Ap + k0, sAb);
    gload_lds16(Ap + (long)64 * K + k0, sAb + 4096);
    gload_lds16(Bp + k0, sBb);
    gload_lds16(Bp + (long)64 * K + k0, sBb + 4096);
    __syncthreads();  // drains vmcnt (global_load_lds) per m97 structure

    bf16x8 a[4], b[4];
#pragma unroll
    for (int i = 0; i < 4; ++i) {
      a[i] = *(const bf16x8*)(sA + (wm * 64 + i * 16 + fr) * 32 + kk);
      b[i] = *(const bf16x8*)(sB + (wn * 64 + i * 16 + fr) * 32 + kk);
    }
#pragma unroll
    for (int i = 0; i < 4; ++i)
#pragma unroll
      for (int j = 0; j < 4; ++j)
        acc[i][j] = __builtin_amdgcn_mfma_f32_16x16x32_bf16(a[i], b[j], acc[i][j], 0, 0, 0);
  }

  // epilogue: C/D layout col=lane&15, row=(lane>>4)*4+reg
  const int cl = lane & 15;
  const int q = lane >> 4;
#pragma unroll
  for (int j = 0; j < 4; ++j) {
    const int colg = bn * 128 + wn * 64 + j * 16 + cl;
    const float bv = bias[colg];
#pragma unroll
    for (int i = 0; i < 4; ++i) {
#pragma unroll
      for (int r = 0; r < 4; ++r) {
        const int rowg = bm * 128 + wm * 64 + i * 16 + q * 4 + r;
        if (rowg < Mstore)
          Cout[(long)rowg * Nout + colg] = acc[i][j][r] + bv;
      }
    }
  }
}

extern "C" void kernel_launch(void* const* d_in, const int* in_sizes, int n_in,
                              void* d_out, int out_size, void* d_ws, size_t ws_size,
                              hipStream_t stream) {
  (void)n_in; (void)ws_size;
  const float* prompt_embs   = (const float*)d_in[0];
  const float* entity_embs   = (const float*)d_in[1];
  const float* neighbor_embs = (const float*)d_in[2];
  const float* relation_embs = (const float*)d_in[3];
  const float* count_table   = (const float*)d_in[4];
  const float* scorer_W      = (const float*)d_in[5];
  const float* scorer_b      = (const float*)d_in[6];
  const float* rel_W         = (const float*)d_in[7];
  const float* rel_b         = (const float*)d_in[8];
  const float* ent_W         = (const float*)d_in[9];
  const float* ent_b         = (const float*)d_in[10];
  const int* counts          = (const int*)d_in[11];
  const int* prompt_indices  = (const int*)d_in[12];
  const int* entity_indices  = (const int*)d_in[13];

  const int D   = in_sizes[5] / 5;   // 768
  const int P   = in_sizes[0] / D;   // 64
  const int C   = in_sizes[4] / D;   // 1000
  const int N   = in_sizes[11];      // 100000
  const int OUT = in_sizes[8];       // 5120
  const int E   = out_size / (2 * OUT);  // 10000
  const int Mp  = ((E + 127) / 128) * 128;  // 10112

  char* ws = (char*)d_ws;
  auto alloc = [&](size_t bytes) {
    char* p = ws;
    ws += (bytes + 255) & ~(size_t)255;
    return p;
  };
  float* sp       = (float*)alloc((size_t)P * 4);
  float* sc       = (float*)alloc((size_t)C * 4);
  float* score    = (float*)alloc((size_t)N * 4);
  int*   segstart = (int*)alloc((size_t)(E + 1) * 4);
  __bf16* ent_agg = (__bf16*)alloc((size_t)Mp * D * 2);
  __bf16* rel_agg = (__bf16*)alloc((size_t)Mp * 2 * D * 2);
  __bf16* relWb   = (__bf16*)alloc((size_t)OUT * 2 * D * 2);
  __bf16* entWb   = (__bf16*)alloc((size_t)OUT * D * 2);

  float* rel_out = (float*)d_out;
  float* ent_out = rel_out + (size_t)E * OUT;

  // weight conversions
  {
    long n4 = (long)OUT * 2 * D / 4;
    convert_bf16_kernel<<<(int)((n4 + 255) / 256), 256, 0, stream>>>(rel_W, relWb, n4);
    n4 = (long)OUT * D / 4;
    convert_bf16_kernel<<<(int)((n4 + 255) / 256), 256, 0, stream>>>(ent_W, entWb, n4);
  }
  // prompt/count partial scores
  {
    int rows = P + C;
    pc_kernel<<<(rows * 64 + 255) / 256, 256, 0, stream>>>(
        prompt_embs, count_table, scorer_W, sp, sc, P, C, D);
  }
  // per-edge scores (one wave per edge)
  score_kernel<<<(N + 3) / 4, 256, 0, stream>>>(
      entity_embs, neighbor_embs, relation_embs, scorer_W, scorer_b,
      sp, sc, counts, prompt_indices, score, N, D);
  // segment boundaries
  segstart_kernel<<<(N + 256) / 256, 256, 0, stream>>>(entity_indices, segstart, N, E);
  // segment softmax + aggregation (padded blocks write zero rows)
  agg_kernel<<<Mp, 192, 0, stream>>>(
      entity_embs, relation_embs, count_table, counts, score, segstart,
      ent_agg, rel_agg, E, D);
  // projectors
  dim3 g(Mp / 128, OUT / 128);
  gemm_bt_bias<<<g, 256, 0, stream>>>(rel_agg, relWb, rel_b, rel_out, 2 * D, OUT, E);
  gemm_bt_bias<<<g, 256, 0, stream>>>(ent_agg, entWb, ent_b, ent_out, D, OUT, E);
}